// Round 5
// baseline (153.061 us; speedup 1.0000x reference)
//
#include <hip/hip_runtime.h>
#include <math.h>

#define NATOM 286
#define NB2   2
#define NN    81796          /* 286*286 */
#define ECAP  82082          /* 2 * 286*287/2 : max unordered pairs incl. self */
#define PW_STRIDE 61440      /* u16 per conv: W2 25600 + W3 25600 + Wo 10240 */
#define PW_OUT_OFF 51200
#define EDGE_BLOCKS 640      /* ceil(NB2*NN / 256) */
#define PREP_BLOCKS 128

typedef unsigned short u16;
typedef unsigned int   u32;

using bf16x8 = __attribute__((ext_vector_type(8))) short;
using f32x4  = __attribute__((ext_vector_type(4))) float;

// Softplus(beta=5), stable: (max(z,0) + log(1+exp(-|z|)))/5
__device__ __forceinline__ float sp5(float x) {
    float z = 5.0f * x;
    return (fmaxf(z, 0.0f) + __logf(1.0f + __expf(-fabsf(z)))) * 0.2f;
}
__device__ __forceinline__ u16 f2bf(float x) {           // RTNE fp32->bf16
    union { float f; u32 u; } v; v.f = x;
    return (u16)((v.u + 0x7FFFu + ((v.u >> 16) & 1u)) >> 16);
}
__device__ __forceinline__ float bf2f(u16 u) {
    union { u32 u; float f; } v; v.u = ((u32)u) << 16;
    return v.f;
}

// ---------------- merged prep + edge ---------------------------------------
// Blocks [0, EDGE_BLOCKS): edge compaction (ballot, 1 atomic/block).
// Blocks [EDGE_BLOCKS, EDGE_BLOCKS+PREP_BLOCKS): f0 gather, f1..f3 zero,
//   weight packing into MFMA B-fragment order. cnt/done pre-zeroed by memset.
__global__ void prep_edge_kernel(const float* __restrict__ xyz,
                                 const int* __restrict__ Z, const float* __restrict__ emb,
                                 const float* w2a, const float* w3a, const float* woa,
                                 const float* w2b, const float* w3b, const float* wob,
                                 const float* w2c, const float* w3c, const float* woc,
                                 float* __restrict__ f0, float* __restrict__ f123,
                                 float4* __restrict__ edges, int* __restrict__ cnt,
                                 u16* __restrict__ PW) {
    const int tid = threadIdx.x;
    if (blockIdx.x < EDGE_BLOCKS) {
        // ---------------- edge part ----------------
        int idx = blockIdx.x * blockDim.x + tid;
        int lane = tid & 63, wv = tid >> 6;
        bool hit = false;
        float b0 = 0.0f, b1 = 0.0f, b2 = 0.0f;
        int meta = -1;
        if (idx < NB2 * NN) {
            int b = idx / NN;
            int rem = idx - b * NN;
            int a = rem / NATOM;
            int n = rem - a * NATOM;
            if (n >= a) {
                const float* pa = xyz + (size_t)(b * NATOM + a) * 3;
                const float* pn = xyz + (size_t)(b * NATOM + n) * 3;
                float dx = pa[0] - pn[0];
                float dy = pa[1] - pn[1];
                float dz = pa[2] - pn[2];
                float d = sqrtf(dx * dx + dy * dy + dz * dz + 1e-12f);
                if (d <= 3.0f) {
                    hit = true;
                    meta = idx;
                    float bas[3];
                    #pragma unroll
                    for (int k = 0; k < 3; ++k) {
                        float x = (d - 1.5f * (float)k) * (1.0f / 1.5f);
                        float v = 0.0f;
                        if (fabsf(x) < 1.0f) {
                            float ct = cosf(1.5707963267948966f * x);
                            v = ct * ct;
                        }
                        bas[k] = v;
                    }
                    b0 = bas[0]; b1 = bas[1]; b2 = bas[2];
                }
            }
        }
        unsigned long long m = __ballot(hit);
        int nw = __popcll(m);
        int before = __popcll(m & ((1ull << lane) - 1ull));
        __shared__ int wb[4];
        __shared__ int gb;
        if (lane == 0) wb[wv] = nw;
        __syncthreads();
        if (tid == 0) gb = atomicAdd(cnt, wb[0] + wb[1] + wb[2] + wb[3]);
        __syncthreads();
        int base = gb + before;
        for (int w = 0; w < wv; ++w) base += wb[w];
        if (hit) edges[base] = make_float4(__int_as_float(meta), b0, b1, b2);
        return;
    }

    // ---------------- prep part ----------------
    int idx = (blockIdx.x - EDGE_BLOCKS) * blockDim.x + tid;
    int stride = PREP_BLOCKS * blockDim.x;
    for (int i = idx; i < NB2 * NATOM * 4; i += stride)
        f0[i] = emb[Z[i >> 2] * 4 + (i & 3)];
    for (int i = idx; i < NB2 * NATOM * 8 * 3; i += stride)
        f123[i] = 0.0f;

    const float SH = 0.08164965809277261f;   // 1/sqrt(150)
    const float* W2s[3] = {w2a, w2b, w2c};
    const float* W3s[3] = {w3a, w3b, w3c};
    const float* Wos[3] = {woa, wob, woc};
    const int   TOUTs[3] = {32, 64, 64};
    const float SDs[3]  = {0.5f, 0.3535533905932738f, 0.3535533905932738f};

    for (int c = 0; c < 3; ++c) {
        u16* base = PW + c * PW_STRIDE;
        for (int which = 0; which < 2; ++which) {       // W2, W3 (150x150)
            const float* src = which ? W3s[c] : W2s[c];
            u16* dst = base + which * 25600;
            for (int d = idx; d < 25600; d += stride) {
                int j = d & 7, lane = (d >> 3) & 63, rest = d >> 9;
                int k0 = rest % 5, nt = rest / 5;
                int n = nt * 16 + (lane & 15);
                int k = k0 * 32 + (lane >> 4) * 8 + j;
                float v = (k < 150 && n < 150) ? src[k * 150 + n] * SH : 0.0f;
                dst[d] = f2bf(v);
            }
        }
        const float* src = Wos[c];                      // Wo (150 x TOUT)
        const int TOUT = TOUTs[c];
        const float sc = SH * SDs[c];                   // fold 1/sqrt(d_in) too
        u16* dst = base + PW_OUT_OFF;
        const int tot = (TOUT / 16) * 5 * 512;
        for (int d = idx; d < tot; d += stride) {
            int j = d & 7, lane = (d >> 3) & 63, rest = d >> 9;
            int k0 = rest % 5, nt = rest / 5;
            int n = nt * 16 + (lane & 15);
            int k = k0 * 32 + (lane >> 4) * 8 + j;
            float v = (k < 150) ? src[k * TOUT + n] * sc : 0.0f;
            dst[d] = f2bf(v);
        }
    }
}

// ---------------- MFMA helpers ---------------------------------------------
// A frag (X[m][k], row stride 168 u16): lane holds X[m=lane&15][k0*32+(lane>>4)*8+j]
__device__ __forceinline__ void load_a(bf16x8 a[5], const u16* X, int m_off, int lane) {
    const int arow = (m_off + (lane & 15)) * 168 + (lane >> 4) * 8;
    #pragma unroll
    for (int k0 = 0; k0 < 5; ++k0)
        a[k0] = *(const bf16x8*)(X + arow + k0 * 32);
}
__device__ __forceinline__ f32x4 mfma_nt(const bf16x8 a[5], const u16* __restrict__ Bp,
                                         int nt, int lane) {
    f32x4 acc = {0.0f, 0.0f, 0.0f, 0.0f};
    #pragma unroll
    for (int k0 = 0; k0 < 5; ++k0) {
        bf16x8 b = *(const bf16x8*)(Bp + ((nt * 5 + k0) * 64 + lane) * 8);
        acc = __builtin_amdgcn_mfma_f32_16x16x32_bf16(a[k0], b, acc, 0, 0, 0);
    }
    return acc;
}
// one hidden layer: Y = sp5(X @ Wp)   (scale folded into Wp)
__device__ __forceinline__ void mfma_layer(const u16* X, u16* Y,
                                           const u16* __restrict__ Bp,
                                           int m_off, int nh, int lane) {
    bf16x8 a[5];
    load_a(a, X, m_off, lane);
    const int quad = lane >> 4;
    const int n_lane = lane & 15;
    #pragma unroll
    for (int i = 0; i < 5; ++i) {
        int nt = nh * 5 + i;
        f32x4 acc = mfma_nt(a, Bp, nt, lane);
        // C/D: col = lane&15, row = quad*4 + r   [measured m89/m91]
        int wb = (m_off + quad * 4) * 168 + nt * 16 + n_lane;
        #pragma unroll
        for (int r = 0; r < 4; ++r)
            Y[wb + r * 168] = f2bf(sp5(acc[r]));
    }
}

// ---------------- radial MLP (MFMA) for all 3 convs + fused conv0 scatter ---
// 32-edge tiles; 256 threads = 4 waves = (m-half 0/1) x (n-half 0/1).
// Grid 1024: 1 item per block for any realistic E; 4 blocks/CU resident.
__global__ __launch_bounds__(256, 4)
void radial_kernel(const float* __restrict__ W1_0, const float* __restrict__ W1_1,
                   const float* __restrict__ W1_2, const u16* __restrict__ PW,
                   const float* __restrict__ f0, float* __restrict__ f1,
                   u16* __restrict__ Kc1, u16* __restrict__ Kc2,
                   const float4* __restrict__ edges, const int* __restrict__ cnt) {
    __shared__ __align__(16) u16 XA[32 * 168];
    __shared__ __align__(16) u16 XB[32 * 168];
    __shared__ float basL[32][3];
    __shared__ int metaL[32];

    const int tid = threadIdx.x;
    const int lane = tid & 63;
    const int wv = tid >> 6;
    const int m_off = (wv & 1) * 16;
    const int nh = wv >> 1;
    const int n_lane = lane & 15;
    const int quad = lane >> 4;
    const float S1 = 0.5773502691896258f;    // 1/sqrt(3)

    const int E = cnt[0];
    const int ntile = (E + 31) >> 5;
    const int items = 3 * ntile;

    for (int item = blockIdx.x; item < items; item += gridDim.x) {
        const int conv = (item < ntile) ? 0 : ((item < 2 * ntile) ? 1 : 2);
        const int tile = item - conv * ntile;
        const int base = tile << 5;
        const u16* Bc = PW + conv * PW_STRIDE;
        const float* W1 = (conv == 0) ? W1_0 : ((conv == 1) ? W1_1 : W1_2);

        __syncthreads();                      // protect LDS reuse across items
        if (tid < 32) {
            int ge = base + tid;
            if (ge < E) {
                float4 v = edges[ge];
                metaL[tid] = __float_as_int(v.x);
                basL[tid][0] = v.y; basL[tid][1] = v.z; basL[tid][2] = v.w;
            } else {
                metaL[tid] = -1;
                basL[tid][0] = 0.0f; basL[tid][1] = 0.0f; basL[tid][2] = 0.0f;
            }
        }
        __syncthreads();

        // ---- layer 1 (scalar fp32, tiny K=3) -> XA (bf16), zero pads
        {
            int e = tid >> 3;
            int kb = (tid & 7) * 20;
            float b0 = basL[e][0], b1 = basL[e][1], b2 = basL[e][2];
            #pragma unroll 4
            for (int i = 0; i < 20; ++i) {
                int k = kb + i;
                float v = 0.0f;
                if (k < 150)
                    v = sp5(S1 * (b0 * W1[k] + b1 * W1[150 + k] + b2 * W1[300 + k]));
                XA[e * 168 + k] = f2bf(v);
            }
        }
        __syncthreads();

        mfma_layer(XA, XB, Bc, m_off, nh, lane);           // layer 2
        __syncthreads();
        mfma_layer(XB, XA, Bc + 25600, m_off, nh, lane);   // layer 3
        __syncthreads();

        // ---- output layer (no activation; 1/sqrt(150), 1/sqrt(din) folded)
        const u16* Bo = Bc + PW_OUT_OFF;
        if (conv == 0) {
            // TOUT=32: wave (m, nh) computes nt = nh
            bf16x8 a[5];
            load_a(a, XA, m_off, lane);
            f32x4 acc = mfma_nt(a, Bo, nh, lane);
            float* YF = (float*)XB;                         // 32 x 33 fp32
            #pragma unroll
            for (int r = 0; r < 4; ++r)
                YF[(m_off + quad * 4 + r) * 33 + nh * 16 + n_lane] = acc[r];
            __syncthreads();
            // fused scatter0: f1[a] += K.f0[n]; f1[n] += K.f0[a]
            int e = tid >> 3, i = tid & 7;
            int meta = metaL[e];
            if (meta >= 0) {
                int b = meta / NN;
                int rm = meta - b * NN;
                int aa = rm / NATOM;
                int nn2 = rm - aa * NATOM;
                const float* Kr = &YF[e * 33 + i * 4];
                const float* fn = f0 + (size_t)(b * NATOM + nn2) * 4;
                float d1 = Kr[0] * fn[0] + Kr[1] * fn[1] + Kr[2] * fn[2] + Kr[3] * fn[3];
                atomicAdd(&f1[(size_t)(b * NATOM + aa) * 8 + i], d1);
                if (nn2 != aa) {
                    const float* fa = f0 + (size_t)(b * NATOM + aa) * 4;
                    float d2 = Kr[0] * fa[0] + Kr[1] * fa[1] + Kr[2] * fa[2] + Kr[3] * fa[3];
                    atomicAdd(&f1[(size_t)(b * NATOM + nn2) * 8 + i], d2);
                }
            }
        } else {
            // TOUT=64: wave handles nt = nh*2, nh*2+1; K -> LDS bf16 -> bulk store
            bf16x8 a[5];
            load_a(a, XA, m_off, lane);
            u16* KB = XB;                                   // 32 x 64 bf16
            #pragma unroll
            for (int t2 = 0; t2 < 2; ++t2) {
                int nt = nh * 2 + t2;
                f32x4 acc = mfma_nt(a, Bo, nt, lane);
                #pragma unroll
                for (int r = 0; r < 4; ++r)
                    KB[(m_off + quad * 4 + r) * 64 + nt * 16 + n_lane] = f2bf(acc[r]);
            }
            __syncthreads();
            u16* Kc = (conv == 1) ? Kc1 : Kc2;
            *(uint4*)(Kc + (size_t)base * 64 + tid * 8) = *(const uint4*)(KB + tid * 8);
        }
    }
}

// ---------------- scatter (bf16 K, DIN=8): f_out[a]+=K.f[n]; f_out[n]+=K.f[a]
__device__ __forceinline__ void scatter_body(const u16* __restrict__ Kc,
                                             const float* __restrict__ f_in,
                                             float* __restrict__ f_out,
                                             const float4* __restrict__ edges, int E) {
    const int total = E * 8;
    for (int idx = blockIdx.x * blockDim.x + threadIdx.x; idx < total;
         idx += gridDim.x * blockDim.x) {
        int e = idx >> 3, i = idx & 7;
        int meta = __float_as_int(edges[e].x);
        int b = meta / NN;
        int rm = meta - b * NN;
        int a = rm / NATOM;
        int n = rm - a * NATOM;
        float kr[8];
        const u16* kp = Kc + (size_t)e * 64 + i * 8;
        #pragma unroll
        for (int j = 0; j < 8; ++j) kr[j] = bf2f(kp[j]);
        const float* fn = f_in + (size_t)(b * NATOM + n) * 8;
        float d1 = 0.0f;
        #pragma unroll
        for (int j = 0; j < 8; ++j) d1 += kr[j] * fn[j];
        atomicAdd(&f_out[(size_t)(b * NATOM + a) * 8 + i], d1);
        if (n != a) {
            const float* fa = f_in + (size_t)(b * NATOM + a) * 8;
            float d2 = 0.0f;
            #pragma unroll
            for (int j = 0; j < 8; ++j) d2 += kr[j] * fa[j];
            atomicAdd(&f_out[(size_t)(b * NATOM + n) * 8 + i], d2);
        }
    }
}

__global__ void scatter_bf16(const u16* __restrict__ Kc, const float* __restrict__ f_in,
                             float* __restrict__ f_out, const float4* __restrict__ edges,
                             const int* __restrict__ cnt) {
    scatter_body(Kc, f_in, f_out, edges, cnt[0]);
}

// ---------------- scatter2 + fused epilogue (last-done-block) ---------------
// lp_pool + linear + BN(batch of 2) + LeakyReLU, run by the last block to
// finish its scatter portion (device-scope atomic + threadfence handshake).
__global__ void scatter2_epilogue(const u16* __restrict__ Kc, const float* __restrict__ f_in,
                                  float* __restrict__ f_out, const float4* __restrict__ edges,
                                  const int* __restrict__ cnt, int* __restrict__ done,
                                  const float* __restrict__ f1, const float* __restrict__ f2,
                                  const float* __restrict__ lin_w, const float* __restrict__ lin_b,
                                  const float* __restrict__ bn_g, const float* __restrict__ bn_b,
                                  float* __restrict__ out) {
    scatter_body(Kc, f_in, f_out, edges, cnt[0]);

    __shared__ int amlast;
    int tid = threadIdx.x;
    __syncthreads();
    if (tid == 0) {
        __threadfence();                       // release: my f3 atomics visible
        int old = atomicAdd(done, 1);
        amlast = (old == (int)gridDim.x - 1);
    }
    __syncthreads();
    if (!amlast) return;
    __threadfence();                           // acquire: all f3 atomics visible

    const float* f3 = f_out;
    __shared__ float ps[240];
    __shared__ float pooled[48];
    __shared__ float yv[48];
    if (tid < 240) {
        int ch = tid % 48, seg = tid / 48;
        int b = ch / 24, cc = ch % 24;
        const float* src = (cc < 8)  ? (f1 + (size_t)(b * NATOM) * 8 + cc)
                         : (cc < 16) ? (f2 + (size_t)(b * NATOM) * 8 + (cc - 8))
                                     : (f3 + (size_t)(b * NATOM) * 8 + (cc - 16));
        int n0 = seg * 58, n1 = (286 < n0 + 58) ? 286 : (n0 + 58);
        float s = 0.0f;
        for (int n = n0; n < n1; ++n) { float v = src[(size_t)n * 8]; s += v * v; }
        ps[tid] = s;
    }
    __syncthreads();
    if (tid < 48)
        pooled[tid] = sqrtf(ps[tid] + ps[tid + 48] + ps[tid + 96] + ps[tid + 144]
                            + ps[tid + 192] + 1e-12f);
    __syncthreads();
    if (tid < 48) {
        int b = tid / 24, o = tid % 24;
        float y = lin_b[o];
        for (int cc = 0; cc < 24; ++cc) y += pooled[b * 24 + cc] * lin_w[o * 24 + cc];
        yv[b * 24 + o] = y;
    }
    __syncthreads();
    if (tid < 24) {
        int o = tid;
        float y0 = yv[o], y1 = yv[24 + o];
        float m = 0.5f * (y0 + y1);
        float v = 0.5f * ((y0 - m) * (y0 - m) + (y1 - m) * (y1 - m));
        float inv = rsqrtf(v + 1e-5f);
        float g = bn_g[o], bb = bn_b[o];
        float t0 = (y0 - m) * inv * g + bb;
        float t1 = (y1 - m) * inv * g + bb;
        out[o]      = t0 > 0.0f ? t0 : 0.2f * t0;
        out[24 + o] = t1 > 0.0f ? t1 : 0.2f * t1;
    }
}

extern "C" void kernel_launch(void* const* d_in, const int* in_sizes, int n_in,
                              void* d_out, int out_size, void* d_ws, size_t ws_size,
                              hipStream_t stream) {
    const float* xyz  = (const float*)d_in[0];
    const int*   Z    = (const int*)d_in[1];
    const float* emb  = (const float*)d_in[2];
    const float* c0w1 = (const float*)d_in[3];
    const float* c0w2 = (const float*)d_in[4];
    const float* c0w3 = (const float*)d_in[5];
    const float* c0wo = (const float*)d_in[6];
    const float* c1w1 = (const float*)d_in[7];
    const float* c1w2 = (const float*)d_in[8];
    const float* c1w3 = (const float*)d_in[9];
    const float* c1wo = (const float*)d_in[10];
    const float* c2w1 = (const float*)d_in[11];
    const float* c2w2 = (const float*)d_in[12];
    const float* c2w3 = (const float*)d_in[13];
    const float* c2wo = (const float*)d_in[14];
    const float* linw = (const float*)d_in[15];
    const float* linb = (const float*)d_in[16];
    const float* bng  = (const float*)d_in[17];
    const float* bnb  = (const float*)d_in[18];
    float* outp = (float*)d_out;

    // ws: [cnt|done 16B][edges][f0][f1][f2][f3][PW bf16][Kc1][Kc2]  (~23 MB)
    char* ws = (char*)d_ws;
    int* cnt = (int*)ws;
    int* done = (int*)(ws + 4);
    float4* edges = (float4*)(ws + 16);
    size_t off = 16 + (size_t)ECAP * 16;
    float* f0 = (float*)(ws + off); off += (size_t)NB2 * NATOM * 4 * 4;
    float* f1 = (float*)(ws + off); off += (size_t)NB2 * NATOM * 8 * 4;
    float* f2 = (float*)(ws + off); off += (size_t)NB2 * NATOM * 8 * 4;
    float* f3 = (float*)(ws + off); off += (size_t)NB2 * NATOM * 8 * 4;
    off = (off + 255) & ~(size_t)255;
    u16* PW = (u16*)(ws + off); off += (size_t)3 * PW_STRIDE * 2;
    off = (off + 255) & ~(size_t)255;
    u16* Kc1 = (u16*)(ws + off); off += (size_t)ECAP * 128;
    u16* Kc2 = (u16*)(ws + off);

    hipMemsetAsync(ws, 0, 16, stream);       // cnt + done
    prep_edge_kernel<<<EDGE_BLOCKS + PREP_BLOCKS, 256, 0, stream>>>(
        xyz, Z, emb, c0w2, c0w3, c0wo, c1w2, c1w3, c1wo, c2w2, c2w3, c2wo,
        f0, f1, edges, cnt, PW);
    radial_kernel<<<1024, 256, 0, stream>>>(c0w1, c1w1, c2w1, PW, f0, f1,
                                            Kc1, Kc2, edges, cnt);
    scatter_bf16<<<256, 256, 0, stream>>>(Kc1, f1, f2, edges, cnt);
    scatter2_epilogue<<<256, 256, 0, stream>>>(Kc2, f2, f3, edges, cnt, done,
                                               f1, f2, linw, linb, bng, bnb, outp);
}